// Round 4
// baseline (15553.162 us; speedup 1.0000x reference)
//
#include <hip/hip_runtime.h>

#define WGSZ 512
#define NWG  64

namespace {
constexpr int kN = 2048, kH = 256, kOO = 4096, kGW = 512;
// Transposed-weight workspace offsets (floats)
constexpr size_t OFF_ELA2 = 0;          // 4x256x256   -> R=1024 K4=64
constexpr size_t OFF_ELM1 = 262144;     // 4x256x4096  -> R=1024 K4=1024
constexpr size_t OFF_ELM2 = 4456448;    // 4x256x256
constexpr size_t OFF_EBL1 = 4718592;    // 4x256x512   -> R=1024 K4=128
constexpr size_t OFF_EBL2 = 5242880;
constexpr size_t OFF_DM1  = 5505024;
constexpr size_t OFF_DV1  = 5767168;
constexpr size_t OFF_WIH  = 6029312;    // 4x2x1024x256 -> R=8192 K4=64
constexpr size_t OFF_WHH  = 8126464;
constexpr size_t WS_FLOATS = 10223616;  // ~39 MB
}

// np.argmin(|centers - v|), first index on tie; centers in exact np fp32 order.
__device__ __forceinline__ int bin_idx(float v) {
  float t = fmaf(v, 5.0f, 63.5f);
  int i0 = (int)floorf(t);
  int c0 = i0 - 1; c0 = c0 < 0 ? 0 : (c0 > 127 ? 127 : c0);
  int c1 = i0;     c1 = c1 < 0 ? 0 : (c1 > 127 ? 127 : c1);
  int c2 = i0 + 1; c2 = c2 < 0 ? 0 : (c2 > 127 ? 127 : c2);
  float d0 = fabsf(__fmul_rn(__fadd_rn((float)(c0 - 64), 0.5f), 0.2f) - v);
  float d1 = fabsf(__fmul_rn(__fadd_rn((float)(c1 - 64), 0.5f), 0.2f) - v);
  float d2 = fabsf(__fmul_rn(__fadd_rn((float)(c2 - 64), 0.5f), 0.2f) - v);
  int best = c0; float bd = d0;
  if (d1 < bd) { bd = d1; best = c1; }
  if (d2 < bd) { bd = d2; best = c2; }
  return best;
}

// numpy pairwise_sum, exact replication for n=128 (LayerNorm only).
__device__ __forceinline__ float np_pw128(const float* a) {
  float r0=a[0],r1=a[1],r2=a[2],r3=a[3],r4=a[4],r5=a[5],r6=a[6],r7=a[7];
  for (int i = 8; i < 128; i += 8) {
    r0=__fadd_rn(r0,a[i+0]); r1=__fadd_rn(r1,a[i+1]);
    r2=__fadd_rn(r2,a[i+2]); r3=__fadd_rn(r3,a[i+3]);
    r4=__fadd_rn(r4,a[i+4]); r5=__fadd_rn(r5,a[i+5]);
    r6=__fadd_rn(r6,a[i+6]); r7=__fadd_rn(r7,a[i+7]);
  }
  return __fadd_rn(__fadd_rn(__fadd_rn(r0,r1),__fadd_rn(r2,r3)),
                   __fadd_rn(__fadd_rn(r4,r5),__fadd_rn(r6,r7)));
}
__device__ __forceinline__ float np_sum256(const float* a) {
  return __fadd_rn(np_pw128(a), np_pw128(a + 128));
}

__device__ __forceinline__ float sig_np(float x) {
  return __fdiv_rn(1.0f, __fadd_rn(1.0f, expf(-x)));
}

__device__ __forceinline__ void fma4(float& aa, float4 w, float4 v) {
  aa = fmaf(w.x, v.x, aa); aa = fmaf(w.y, v.y, aa);
  aa = fmaf(w.z, v.z, aa); aa = fmaf(w.w, v.w, aa);
}
__device__ __forceinline__ void add4(float& aa, float4 w) {
  aa = __fadd_rn(__fadd_rn(__fadd_rn(__fadd_rn(aa, w.x), w.y), w.z), w.w);
}

// Exact ascending-k single-chain dot, deep-pipelined: load 16 float4 into
// registers (compile-time indices -> no scratch), then FMA them. SK is the
// compile-time float4 stride between successive k (1 = original layout,
// R = transposed layout).
template<int SK>
__device__ __forceinline__ float dotT(const float4* __restrict__ w4, size_t base,
                                      const float4* __restrict__ x4, int nf4,
                                      float acc) {
  float4 wb[16];
  for (int blk = 0; blk < nf4; blk += 16) {
    #pragma unroll
    for (int j = 0; j < 16; ++j) wb[j] = w4[base + (size_t)(blk + j) * SK];
    #pragma unroll
    for (int j = 0; j < 16; ++j) fma4(acc, wb[j], x4[blk + j]);
  }
  return acc;
}
// Exact ascending plain sum of 256 weights (h = ones case), 64 float4.
template<int SK>
__device__ __forceinline__ float sumT(const float4* __restrict__ w4, size_t base) {
  float acc = 0.0f;
  float4 wb[16];
  for (int blk = 0; blk < 64; blk += 16) {
    #pragma unroll
    for (int j = 0; j < 16; ++j) wb[j] = w4[base + (size_t)(blk + j) * SK];
    #pragma unroll
    for (int j = 0; j < 16; ++j) add4(acc, wb[j]);
  }
  return acc;
}
// elm hidden: K=4096 (1024 float4), 32-deep pipeline.
template<int SK>
__device__ __forceinline__ float dotElm(const float4* __restrict__ w4, size_t base,
                                        const float4* __restrict__ x4) {
  float acc = 0.0f;
  float4 wb[32];
  for (int blk = 0; blk < 1024; blk += 32) {
    #pragma unroll
    for (int j = 0; j < 32; ++j) wb[j] = w4[base + (size_t)(blk + j) * SK];
    #pragma unroll
    for (int j = 0; j < 32; ++j) fma4(acc, wb[j], x4[blk + j]);
  }
  return acc;
}

// ---------------- transpose pre-pass ----------------
struct TransArgs {
  const float* src[9];
  float*       dst[9];
  int          n4[9];      // R*K4 float4 count
  int          rmask[9];   // R-1 (R pow2)
  int          rshift[9];  // log2(R)
  int          K[9];
};

__global__ void transpose_all(TransArgs a) {
  const int gtid = blockIdx.x * blockDim.x + threadIdx.x;
  const int gsz  = gridDim.x * blockDim.x;
  for (int m = 0; m < 9; ++m) {
    const float* __restrict__ src = a.src[m];
    float4* __restrict__ dst = (float4*)a.dst[m];
    const int n = a.n4[m], rm = a.rmask[m], rs = a.rshift[m], K = a.K[m];
    for (int i = gtid; i < n; i += gsz) {
      const int r = i & rm, k4 = i >> rs;
      const float* s = src + (size_t)r * K + (size_t)k4 * 4;
      float4 v; v.x = s[0]; v.y = s[1]; v.z = s[2]; v.w = s[3];
      dst[i] = v;
    }
  }
}

// 512 threads (8 waves) per WG, 1 WG/CU, VGPR budget 256 for deep load
// pipelines. Thread-per-row ascending chains -> exact numerics.
template<int USET>
__global__ __launch_bounds__(WGSZ, 2) void planner_kernel(
    const float* __restrict__ inp_start, const float* __restrict__ map_pts,
    const float* __restrict__ ela_w1, const float* __restrict__ ela_w2,
    const float* __restrict__ conv_w, const float* __restrict__ elm_w1,
    const float* __restrict__ elm_w2, const float* __restrict__ ebl_w1,
    const float* __restrict__ ebl_w2, const float* __restrict__ lstm_wih,
    const float* __restrict__ lstm_whh, const float* __restrict__ dm_w1,
    const float* __restrict__ dm_w2, const float* __restrict__ dv_w1,
    const float* __restrict__ dv_w2, const float* __restrict__ wsT,
    float* __restrict__ g_out) {
  const int b   = blockIdx.x;
  const int tid = threadIdx.x;

  __shared__ unsigned s_mask[kGW];
  __shared__ __align__(16) float s_conv[kOO];   // 16KB
  __shared__ __align__(16) float s_cw[800];     // conv weights (raw)
  __shared__ __align__(16) float s_elah[kH], s_elao[kH], s_elmh[kH], s_elmo[kH];
  __shared__ __align__(16) float s_eblh[kH], s_eblo[kH];
  __shared__ __align__(16) float s_h0[kH], s_c0[kH], s_h1[kH], s_c1[kH];
  __shared__ __align__(16) float s_gate[1024];
  __shared__ __align__(16) float s_tmp[512];    // LN: d, d^2
  __shared__ __align__(16) float s_r[kH], s_dmh[kH], s_dvh[kH];
  __shared__ float s_anchor[3], s_cs[2], s_g6[6];
  __shared__ float s_mu, s_den;

  // ---- init ----
  if (tid == 0) {
    float a2 = inp_start[b * 3 + 2];
    s_anchor[0] = inp_start[b * 3 + 0];
    s_anchor[1] = inp_start[b * 3 + 1];
    s_anchor[2] = a2;
    s_cs[0] = (float)cos((double)a2);
    s_cs[1] = (float)sin((double)a2);
  }
  if (tid < 3) {
    g_out[b * 96 + tid] = inp_start[b * 3 + tid];
    g_out[6144 + b * 96 + tid] = 0.01f;
  }
  __syncthreads();

  // ================= 28 sequential steps, all batch-local =================
  for (int k = 0; k < 28; ++k) {
    const int st = k / 7, a = k % 7;
    const bool a0f = (a == 0);

    // ---- phase 1: clear mask, stage raw conv weights, ela hidden (K=3) ----
    for (int w = tid; w < kGW; w += WGSZ) s_mask[w] = 0u;
    for (int w = tid; w < 800; w += WGSZ) s_cw[w] = conv_w[st * 800 + w];
    if (tid < kH) {
      const float* w1r = ela_w1 + (st * kH + tid) * 3;
      float h = fmaf(s_anchor[2], w1r[2],
                fmaf(s_anchor[1], w1r[1], __fmul_rn(s_anchor[0], w1r[0])));
      s_elah[tid] = fmaxf(h, 0.0f);
    }
    __syncthreads();

    // ---- phase 2: OGM scatter ----
    {
      float ax = s_anchor[0], ay = s_anchor[1], cc = s_cs[0], ss = s_cs[1];
      for (int n = tid; n < kN; n += WGSZ) {
        float mx = __fadd_rn(map_pts[n],      -ax);
        float my = __fadd_rn(map_pts[kN + n], -ay);
        float px = fmaf(ss, my, __fmul_rn(cc, mx));
        float py = fmaf(cc, my, -__fmul_rn(ss, mx));
        bool outb = (fabsf(px) > 12.8f) || (fabsf(py) > 12.8f);
        px = outb ? 0.0f : px;
        py = outb ? 0.0f : py;
        int xi = bin_idx(px), yi = bin_idx(py);
        atomicOr(&s_mask[xi * 4 + (yi >> 5)], 1u << (yi & 31));
      }
    }
    __syncthreads();

    // ---- phase 3: conv 5x5/s2, EXACT baseline (o,ci,t) chain order ----
    for (int q = 0; q < 8; ++q) {
      const int p = tid + (q << 9);
      const int oy = p >> 6, ox = p & 63;
      unsigned occ = 0u;
      for (int ky = 0; ky < 5; ++ky) {
        const int y = 2 * oy - 2 + ky;
        if ((unsigned)y >= 128u) continue;
        const unsigned* row = &s_mask[y * 4];
        for (int kx = 0; kx < 5; ++kx) {
          const int x = 2 * ox - 2 + kx;
          if ((unsigned)x >= 128u) continue;
          if ((row[x >> 5] >> (x & 31)) & 1u) occ |= 1u << (ky * 5 + kx);
        }
      }
      float csum = 0.0f;
      if (occ != 0u) {
        for (int o = 0; o < 8; ++o) {
          float acc = 0.0f;
          const float* wo = s_cw + o * 100;
          for (int ci = 0; ci < 4; ++ci) {
            const float* wc = wo + ci * 25;
            #pragma unroll
            for (int t = 0; t < 25; ++t)
              acc = __fadd_rn(acc, ((occ >> t) & 1u) ? wc[t] : 0.0f);
          }
          float th = tanhf(acc);
          csum = (o == 0) ? th : __fadd_rn(csum, th);
        }
      }
      s_conv[p] = csum;
    }
    __syncthreads();

    // ---- phase 4: ela out + elm hidden (threads 0-255, deep pipelines) ----
    if (tid < kH) {
      {
        constexpr int SK = USET ? 1024 : 1;
        const float4* w4 = USET ? (const float4*)(wsT + OFF_ELA2)
                                : (const float4*)ela_w2;
        const size_t base = USET ? (size_t)(st * kH + tid)
                                 : (size_t)(st * kH + tid) * 64;
        s_elao[tid] = dotT<SK>(w4, base, (const float4*)s_elah, 64, 0.0f);
      }
      {
        constexpr int SK = USET ? 1024 : 1;
        const float4* w4 = USET ? (const float4*)(wsT + OFF_ELM1)
                                : (const float4*)elm_w1;
        const size_t base = USET ? (size_t)(st * kH + tid)
                                 : (size_t)(st * kH + tid) * 1024;
        float acc = dotElm<SK>(w4, base, (const float4*)s_conv);
        s_elmh[tid] = fmaxf(acc, 0.0f);
      }
    }
    __syncthreads();

    // ---- phase 5: elm out ----
    if (tid < kH) {
      constexpr int SK = USET ? 1024 : 1;
      const float4* w4 = USET ? (const float4*)(wsT + OFF_ELM2)
                              : (const float4*)elm_w2;
      const size_t base = USET ? (size_t)(st * kH + tid)
                               : (size_t)(st * kH + tid) * 64;
      s_elmo[tid] = dotT<SK>(w4, base, (const float4*)s_elmh, 64, 0.0f);
    }
    __syncthreads();

    // ---- phase 6: ebl hidden (K=512, single ascending chain over concat) ----
    if (tid < kH) {
      constexpr int SK = USET ? 1024 : 1;
      const float4* w4 = USET ? (const float4*)(wsT + OFF_EBL1)
                              : (const float4*)ebl_w1;
      const size_t base = USET ? (size_t)(st * kH + tid)
                               : (size_t)(st * kH + tid) * 128;
      float acc = dotT<SK>(w4, base, (const float4*)s_elao, 64, 0.0f);
      acc = dotT<SK>(w4, base + (size_t)64 * SK, (const float4*)s_elmo, 64, acc);
      s_eblh[tid] = fmaxf(acc, 0.0f);
    }
    __syncthreads();

    // ---- phase 7: ebl out ----
    if (tid < kH) {
      constexpr int SK = USET ? 1024 : 1;
      const float4* w4 = USET ? (const float4*)(wsT + OFF_EBL2)
                              : (const float4*)ebl_w2;
      const size_t base = USET ? (size_t)(st * kH + tid)
                               : (size_t)(st * kH + tid) * 64;
      s_eblo[tid] = dotT<SK>(w4, base, (const float4*)s_eblh, 64, 0.0f);
    }
    __syncthreads();

    // ---- LSTM layers: 1024 gate rows, 2 rows/thread (2 parallel chains) ----
    for (int l = 0; l < 2; ++l) {
      {
        const float4* xe4 = (const float4*)((l == 0) ? s_eblo : s_h0);
        const float4* xh4 = (const float4*)((l == 0) ? s_h0 : s_h1);
        constexpr int SKL = USET ? 8192 : 1;
        const float4* wi4 = USET ? (const float4*)(wsT + OFF_WIH)
                                 : (const float4*)lstm_wih;
        const float4* wh4 = USET ? (const float4*)(wsT + OFF_WHH)
                                 : (const float4*)lstm_whh;
        #pragma unroll
        for (int rr = 0; rr < 2; ++rr) {
          const int row = tid + (rr << 9);
          const size_t rgl = (size_t)((st * 2 + l) * 1024 + row);
          const size_t bi = USET ? rgl : rgl * 64;
          float A = dotT<SKL>(wi4, bi, xe4, 64, 0.0f);
          float Bv = a0f ? sumT<SKL>(wh4, bi)
                         : dotT<SKL>(wh4, bi, xh4, 64, 0.0f);
          s_gate[row] = __fadd_rn(A, Bv);
        }
      }
      __syncthreads();
      if (tid < kH) {
        float gi = s_gate[tid], gf = s_gate[256 + tid];
        float gg = s_gate[512 + tid], go = s_gate[768 + tid];
        float* sc = (l == 0) ? s_c0 : s_c1;
        float* sh = (l == 0) ? s_h0 : s_h1;
        float cprev = a0f ? 1.0f : sc[tid];
        float cl = __fadd_rn(__fmul_rn(sig_np(gf), cprev),
                             __fmul_rn(sig_np(gi), tanhf(gg)));
        float hl = __fmul_rn(sig_np(go), tanhf(cl));
        sc[tid] = cl; sh[tid] = hl;
      }
      __syncthreads();
    }

    // ---- LayerNorm (numpy pairwise) + r ----
    if (tid == 0) s_mu = __fdiv_rn(np_sum256(s_h1), 256.0f);
    __syncthreads();
    if (tid < kH) {
      float d = __fadd_rn(s_h1[tid], -s_mu);
      s_tmp[tid] = d;
      s_tmp[256 + tid] = __fmul_rn(d, d);
    }
    __syncthreads();
    if (tid == 0) {
      float v = __fdiv_rn(np_sum256(s_tmp + 256), 256.0f);
      s_den = __fsqrt_rn(__fadd_rn(v, 1e-5f));
    }
    __syncthreads();
    if (tid < kH) {
      float r = __fadd_rn(__fdiv_rn(s_tmp[tid], s_den), s_eblo[tid]);
      s_r[tid] = fmaxf(r, 0.0f);
    }
    __syncthreads();

    // ---- dm/dv hidden: 512 rows across 512 threads ----
    {
      const int r = tid & 255;
      const bool isv = tid >= kH;
      constexpr int SK = USET ? 1024 : 1;
      const float4* w4;
      if (USET) {
        w4 = (const float4*)(wsT + (isv ? OFF_DV1 : OFF_DM1));
      } else {
        w4 = (const float4*)(isv ? dv_w1 : dm_w1);
      }
      const size_t base = USET ? (size_t)(st * kH + r)
                               : (size_t)(st * kH + r) * 64;
      float v = dotT<SK>(w4, base, (const float4*)s_r, 64, 0.0f);
      (isv ? s_dvh : s_dmh)[r] = fmaxf(v, 0.0f);
    }
    __syncthreads();

    // ---- heads (tiny; original layout, exact ascending) ----
    if (tid < 6) {
      const int d = tid % 3; const bool isv = tid >= 3;
      const float* W = (isv ? dv_w2 : dm_w2) + (st * 3 + d) * kH;
      s_g6[tid] = dotT<1>((const float4*)W, 0,
                          (const float4*)(isv ? s_dvh : s_dmh), 64, 0.0f);
    }
    __syncthreads();

    // ---- anchor update + outputs ----
    if (tid == 0) {
      const float dlmf[3] = {2.0f, 2.0f, 0.5f};
      for (int d = 0; d < 3; ++d) {
        float avn = __fadd_rn(s_anchor[d], __fmul_rn(tanhf(s_g6[d]), dlmf[d]));
        float vvn = __fmul_rn(sig_np(s_g6[3 + d]), 0.1f);
        s_anchor[d] = avn;
        int o = ((b * 4 + st) * 8 + (a + 1)) * 3 + d;
        g_out[o] = avn;
        g_out[6144 + o] = vvn;
        if (a == 6 && st < 3) {
          int o2 = ((b * 4 + st + 1) * 8 + 0) * 3 + d;
          g_out[o2] = avn;
          g_out[6144 + o2] = vvn;
        }
      }
      s_cs[0] = (float)cos((double)s_anchor[2]);
      s_cs[1] = (float)sin((double)s_anchor[2]);
    }
    __syncthreads();
  }
}

extern "C" void kernel_launch(void* const* d_in, const int* in_sizes, int n_in,
                              void* d_out, int out_size, void* d_ws, size_t ws_size,
                              hipStream_t stream) {
  (void)in_sizes; (void)n_in; (void)out_size;
  const int useT = (d_ws != nullptr && ws_size >= WS_FLOATS * sizeof(float)) ? 1 : 0;
  float* wsf = (float*)d_ws;

  if (useT) {
    TransArgs ta;
    const float* srcs[9] = {
        (const float*)d_in[3],  // ela_w2
        (const float*)d_in[5],  // elm_w1
        (const float*)d_in[6],  // elm_w2
        (const float*)d_in[7],  // ebl_w1
        (const float*)d_in[8],  // ebl_w2
        (const float*)d_in[11], // dm_w1
        (const float*)d_in[13], // dv_w1
        (const float*)d_in[9],  // lstm_wih
        (const float*)d_in[10]  // lstm_whh
    };
    float* dsts[9] = {
        wsf + OFF_ELA2, wsf + OFF_ELM1, wsf + OFF_ELM2, wsf + OFF_EBL1,
        wsf + OFF_EBL2, wsf + OFF_DM1,  wsf + OFF_DV1,  wsf + OFF_WIH,
        wsf + OFF_WHH
    };
    const int n4s[9]   = {65536, 1048576, 65536, 131072, 65536, 65536, 65536,
                          524288, 524288};
    const int rms[9]   = {1023, 1023, 1023, 1023, 1023, 1023, 1023, 8191, 8191};
    const int rss[9]   = {10, 10, 10, 10, 10, 10, 10, 13, 13};
    const int Ks[9]    = {256, 4096, 256, 512, 256, 256, 256, 256, 256};
    for (int m = 0; m < 9; ++m) {
      ta.src[m] = srcs[m]; ta.dst[m] = dsts[m]; ta.n4[m] = n4s[m];
      ta.rmask[m] = rms[m]; ta.rshift[m] = rss[m]; ta.K[m] = Ks[m];
    }
    transpose_all<<<dim3(1024), dim3(256), 0, stream>>>(ta);

    planner_kernel<1><<<dim3(NWG), dim3(WGSZ), 0, stream>>>(
        (const float*)d_in[0],  (const float*)d_in[1],  (const float*)d_in[2],
        (const float*)d_in[3],  (const float*)d_in[4],  (const float*)d_in[5],
        (const float*)d_in[6],  (const float*)d_in[7],  (const float*)d_in[8],
        (const float*)d_in[9],  (const float*)d_in[10], (const float*)d_in[11],
        (const float*)d_in[12], (const float*)d_in[13], (const float*)d_in[14],
        (const float*)wsf, (float*)d_out);
  } else {
    planner_kernel<0><<<dim3(NWG), dim3(WGSZ), 0, stream>>>(
        (const float*)d_in[0],  (const float*)d_in[1],  (const float*)d_in[2],
        (const float*)d_in[3],  (const float*)d_in[4],  (const float*)d_in[5],
        (const float*)d_in[6],  (const float*)d_in[7],  (const float*)d_in[8],
        (const float*)d_in[9],  (const float*)d_in[10], (const float*)d_in[11],
        (const float*)d_in[12], (const float*)d_in[13], (const float*)d_in[14],
        (const float*)wsf, (float*)d_out);
  }
}

// Round 5
// 9332.928 us; speedup vs baseline: 1.6665x; 1.6665x over previous
//
#include <hip/hip_runtime.h>

#define WGSZ 1024
#define NWG  64

namespace {
constexpr int kN = 2048, kH = 256, kGW = 512;
// Transposed-weight workspace offsets (floats); layout [k4][row] float4s.
constexpr size_t OFF_ELA2 = 0;          // 4x256x256   -> Rg=1024 K4=64
constexpr size_t OFF_ELM1 = 262144;     // 4x256x4096  -> Rg=1024 K4=1024
constexpr size_t OFF_ELM2 = 4456448;    // 4x256x256
constexpr size_t OFF_EBL1 = 4718592;    // 4x256x512   -> Rg=1024 K4=128
constexpr size_t OFF_EBL2 = 5242880;
constexpr size_t OFF_DM1  = 5505024;
constexpr size_t OFF_DV1  = 5767168;
constexpr size_t OFF_WIH  = 6029312;    // 4x2x1024x256 -> Rg=8192 K4=64
constexpr size_t OFF_WHH  = 8126464;
constexpr size_t WS_FLOATS = 10223616;  // ~39 MB
}

// np.argmin(|centers - v|), first index on tie.
__device__ __forceinline__ int bin_idx(float v) {
  float t = fmaf(v, 5.0f, 63.5f);
  int i0 = (int)floorf(t);
  int c0 = i0 - 1; c0 = c0 < 0 ? 0 : (c0 > 127 ? 127 : c0);
  int c1 = i0;     c1 = c1 < 0 ? 0 : (c1 > 127 ? 127 : c1);
  int c2 = i0 + 1; c2 = c2 < 0 ? 0 : (c2 > 127 ? 127 : c2);
  float d0 = fabsf(__fmul_rn(__fadd_rn((float)(c0 - 64), 0.5f), 0.2f) - v);
  float d1 = fabsf(__fmul_rn(__fadd_rn((float)(c1 - 64), 0.5f), 0.2f) - v);
  float d2 = fabsf(__fmul_rn(__fadd_rn((float)(c2 - 64), 0.5f), 0.2f) - v);
  int best = c0; float bd = d0;
  if (d1 < bd) { bd = d1; best = c1; }
  if (d2 < bd) { bd = d2; best = c2; }
  return best;
}

// numpy pairwise_sum, exact replication for n=128 (LayerNorm only).
__device__ __forceinline__ float np_pw128(const float* a) {
  float r0=a[0],r1=a[1],r2=a[2],r3=a[3],r4=a[4],r5=a[5],r6=a[6],r7=a[7];
  for (int i = 8; i < 128; i += 8) {
    r0=__fadd_rn(r0,a[i+0]); r1=__fadd_rn(r1,a[i+1]);
    r2=__fadd_rn(r2,a[i+2]); r3=__fadd_rn(r3,a[i+3]);
    r4=__fadd_rn(r4,a[i+4]); r5=__fadd_rn(r5,a[i+5]);
    r6=__fadd_rn(r6,a[i+6]); r7=__fadd_rn(r7,a[i+7]);
  }
  return __fadd_rn(__fadd_rn(__fadd_rn(r0,r1),__fadd_rn(r2,r3)),
                   __fadd_rn(__fadd_rn(r4,r5),__fadd_rn(r6,r7)));
}
__device__ __forceinline__ float np_sum256(const float* a) {
  return __fadd_rn(np_pw128(a), np_pw128(a + 128));
}

__device__ __forceinline__ float sig_np(float x) {
  return __fdiv_rn(1.0f, __fadd_rn(1.0f, expf(-x)));
}

__device__ __forceinline__ void fma4(float& aa, float4 w, float4 v) {
  aa = fmaf(w.x, v.x, aa); aa = fmaf(w.y, v.y, aa);
  aa = fmaf(w.z, v.z, aa); aa = fmaf(w.w, v.w, aa);
}

// Async global->LDS 16B copy: LDS dst = wave-uniform base + lane*16.
__device__ __forceinline__ void gl_lds(const float4* g, float4* l) {
  __builtin_amdgcn_global_load_lds(
      (__attribute__((address_space(1))) void*)g,
      (__attribute__((address_space(3))) void*)l, 16, 0, 0);
}

// Stage a k4-chunk [c0, c0+ck) of RA rows into LDS as [kk][row].
// wgT: transposed layout (f4 idx = k4*Rg + row) -> lane-contiguous (fast).
// wgO: original row-major fallback (f4 idx = row*k4o + k4) -> slow but exact.
template<int RA>
__device__ __forceinline__ void stage_chunk(float4* dst, const float4* wgT,
                                            const float4* wgO, int k4o,
                                            size_t Rg, int c0, int ck,
                                            int wid, int lane) {
  constexpr int RA64 = RA / 64;
  const int U = ck * RA64;
  if (wgT) {
    for (int u = wid; u < U; u += 16) {
      const int k4l = u / RA64, rg = u % RA64;
      gl_lds(wgT + (size_t)(c0 + k4l) * Rg + rg * 64 + lane, dst + u * 64);
    }
  } else {
    for (int u = wid; u < U; u += 16) {
      const int k4l = u / RA64, rg = u % RA64;
      gl_lds(wgO + (size_t)(rg * 64 + lane) * k4o + c0 + k4l, dst + u * 64);
    }
  }
}

// Double-buffered staged matvec: thread r<RA runs its EXACT ascending fmaf
// chain over K4 float4s; weights flow through LDS via async global_load_lds.
template<int RA>
__device__ float run_matvec(float4 (*wb)[3072], const float4* wgT,
                            const float4* wgO, int k4o, size_t Rg, int K4,
                            const float4* x4, int tid, float acc0) {
  constexpr int CK4 = 3072 / RA;   // 12 (RA=256) or 3 (RA=1024)
  const int wid = tid >> 6, lane = tid & 63;
  float acc = acc0;
  int c0 = 0, ck = (K4 < CK4 ? K4 : CK4), cur = 0;
  stage_chunk<RA>(wb[0], wgT, wgO, k4o, Rg, 0, ck, wid, lane);
  asm volatile("s_waitcnt vmcnt(0)" ::: "memory");
  __syncthreads();
  for (;;) {
    const int nc0 = c0 + ck;
    int nck = K4 - nc0; if (nck > CK4) nck = CK4;
    if (nck > 0)
      stage_chunk<RA>(wb[cur ^ 1], wgT, wgO, k4o, Rg, nc0, nck, wid, lane);
    if (tid < RA) {
      const float4* sb = wb[cur];
      for (int kk = 0; kk < ck; ++kk)
        fma4(acc, sb[kk * RA + tid], x4[c0 + kk]);
    }
    asm volatile("s_waitcnt vmcnt(0)" ::: "memory");
    __syncthreads();
    if (nck <= 0) break;
    c0 = nc0; ck = nck; cur ^= 1;
  }
  return acc;
}

// ---------------- transpose pre-pass ----------------
struct TransArgs {
  const float* src[9];
  float*       dst[9];
  int          n4[9];      // R*K4 float4 count
  int          rmask[9];   // R-1 (R pow2)
  int          rshift[9];  // log2(R)
  int          K[9];
};

__global__ void transpose_all(TransArgs a) {
  const int gtid = blockIdx.x * blockDim.x + threadIdx.x;
  const int gsz  = gridDim.x * blockDim.x;
  for (int m = 0; m < 9; ++m) {
    const float* __restrict__ src = a.src[m];
    float4* __restrict__ dst = (float4*)a.dst[m];
    const int n = a.n4[m], rm = a.rmask[m], rs = a.rshift[m], K = a.K[m];
    for (int i = gtid; i < n; i += gsz) {
      const int r = i & rm, k4 = i >> rs;
      const float* s = src + (size_t)r * K + (size_t)k4 * 4;
      float4 v; v.x = s[0]; v.y = s[1]; v.z = s[2]; v.w = s[3];
      dst[i] = v;
    }
  }
}

template<int USET>
__global__ __launch_bounds__(WGSZ, 4) void planner_kernel(
    const float* __restrict__ inp_start, const float* __restrict__ map_pts,
    const float* __restrict__ ela_w1, const float* __restrict__ ela_w2,
    const float* __restrict__ conv_w, const float* __restrict__ elm_w1,
    const float* __restrict__ elm_w2, const float* __restrict__ ebl_w1,
    const float* __restrict__ ebl_w2, const float* __restrict__ lstm_wih,
    const float* __restrict__ lstm_whh, const float* __restrict__ dm_w1,
    const float* __restrict__ dm_w2, const float* __restrict__ dv_w1,
    const float* __restrict__ dv_w2, const float* __restrict__ wsT,
    float* __restrict__ g_out) {
  const int b   = blockIdx.x;
  const int tid = threadIdx.x;
  const float4* wsf4 = (const float4*)wsT;

  __shared__ __align__(16) float4 s_wbuf[2][3072];   // 2 x 48KB weight chunks
  __shared__ unsigned s_mask[kGW];
  __shared__ __align__(16) float s_conv[4096];
  __shared__ __align__(16) float s_cw[800];
  __shared__ __align__(16) float s_cat[512];         // [elao | elmo]
  __shared__ __align__(16) float s_elah[kH], s_elmh[kH], s_eblh[kH], s_eblo[kH];
  __shared__ __align__(16) float s_h0[kH], s_c0[kH], s_h1[kH], s_c1[kH];
  __shared__ __align__(16) float s_gate[1024];
  __shared__ __align__(16) float s_tmp[512];
  __shared__ __align__(16) float s_r[kH], s_dmh[kH], s_dvh[kH];
  __shared__ __align__(16) float s_ones[kH];
  __shared__ __align__(16) float s_hw[1536];         // dm_w2|dv_w2 st slices
  __shared__ float s_anchor[3], s_cs[2], s_g6[6];
  __shared__ float s_mu, s_den;

  // ---- init ----
  if (tid == 0) {
    float a2 = inp_start[b * 3 + 2];
    s_anchor[0] = inp_start[b * 3 + 0];
    s_anchor[1] = inp_start[b * 3 + 1];
    s_anchor[2] = a2;
    s_cs[0] = (float)cos((double)a2);
    s_cs[1] = (float)sin((double)a2);
  }
  if (tid < kH) s_ones[tid] = 1.0f;
  if (tid < 3) {
    g_out[b * 96 + tid] = inp_start[b * 3 + tid];
    g_out[6144 + b * 96 + tid] = 0.01f;
  }
  __syncthreads();

  for (int k = 0; k < 28; ++k) {
    const int st = k / 7, a = k % 7;
    const bool a0f = (a == 0);

    // ---- phase 1: mask clear, conv-w stage, ela hidden (K=3) ----
    if (tid < kGW) s_mask[tid] = 0u;
    if (tid < 800) s_cw[tid] = conv_w[st * 800 + tid];
    if (tid >= 768 && tid < 768 + kH) {
      const int r = tid - 768;
      const float* w1r = ela_w1 + (st * kH + r) * 3;
      float h = fmaf(s_anchor[2], w1r[2],
                fmaf(s_anchor[1], w1r[1], __fmul_rn(s_anchor[0], w1r[0])));
      s_elah[r] = fmaxf(h, 0.0f);
    }
    __syncthreads();

    // ---- phase 2: OGM scatter ----
    {
      float ax = s_anchor[0], ay = s_anchor[1], cc = s_cs[0], ss = s_cs[1];
      for (int n = tid; n < kN; n += WGSZ) {
        float mx = __fadd_rn(map_pts[n],      -ax);
        float my = __fadd_rn(map_pts[kN + n], -ay);
        float px = fmaf(ss, my, __fmul_rn(cc, mx));
        float py = fmaf(cc, my, -__fmul_rn(ss, mx));
        bool outb = (fabsf(px) > 12.8f) || (fabsf(py) > 12.8f);
        px = outb ? 0.0f : px;
        py = outb ? 0.0f : py;
        int xi = bin_idx(px), yi = bin_idx(py);
        atomicOr(&s_mask[xi * 4 + (yi >> 5)], 1u << (yi & 31));
      }
    }
    __syncthreads();

    // ---- phase 3: conv 5x5/s2, EXACT baseline (o,ci,t) chain order ----
    for (int q = 0; q < 4; ++q) {
      const int p = tid + (q << 10);
      const int oy = p >> 6, ox = p & 63;
      unsigned occ = 0u;
      for (int ky = 0; ky < 5; ++ky) {
        const int y = 2 * oy - 2 + ky;
        if ((unsigned)y >= 128u) continue;
        const unsigned* row = &s_mask[y * 4];
        for (int kx = 0; kx < 5; ++kx) {
          const int x = 2 * ox - 2 + kx;
          if ((unsigned)x >= 128u) continue;
          if ((row[x >> 5] >> (x & 31)) & 1u) occ |= 1u << (ky * 5 + kx);
        }
      }
      float csum = 0.0f;
      if (occ != 0u) {
        for (int o = 0; o < 8; ++o) {
          float acc = 0.0f;
          const float* wo = s_cw + o * 100;
          for (int ci = 0; ci < 4; ++ci) {
            const float* wc = wo + ci * 25;
            #pragma unroll
            for (int t = 0; t < 25; ++t)
              acc = __fadd_rn(acc, ((occ >> t) & 1u) ? wc[t] : 0.0f);
          }
          float th = tanhf(acc);
          csum = (o == 0) ? th : __fadd_rn(csum, th);
        }
      }
      s_conv[p] = csum;
    }
    __syncthreads();

    // ---- phase 4: ela out (staged) -> s_cat[0:256] ----
    {
      const float4* wT = USET ? wsf4 + OFF_ELA2 / 4 + st * 256 : nullptr;
      const float4* wO = USET ? nullptr
                              : (const float4*)ela_w2 + (size_t)(st * 256) * 64;
      float acc = run_matvec<256>(s_wbuf, wT, wO, 64, 1024, 64,
                                  (const float4*)s_elah, tid, 0.0f);
      if (tid < kH) s_cat[tid] = acc;
    }

    // ---- phase 5: elm hidden (K=4096, staged) ----
    {
      const float4* wT = USET ? wsf4 + OFF_ELM1 / 4 + st * 256 : nullptr;
      const float4* wO = USET ? nullptr
                              : (const float4*)elm_w1 + (size_t)(st * 256) * 1024;
      float acc = run_matvec<256>(s_wbuf, wT, wO, 1024, 1024, 1024,
                                  (const float4*)s_conv, tid, 0.0f);
      if (tid < kH) s_elmh[tid] = fmaxf(acc, 0.0f);
    }

    // ---- phase 6: elm out -> s_cat[256:512] ----
    {
      const float4* wT = USET ? wsf4 + OFF_ELM2 / 4 + st * 256 : nullptr;
      const float4* wO = USET ? nullptr
                              : (const float4*)elm_w2 + (size_t)(st * 256) * 64;
      float acc = run_matvec<256>(s_wbuf, wT, wO, 64, 1024, 64,
                                  (const float4*)s_elmh, tid, 0.0f);
      if (tid < kH) s_cat[256 + tid] = acc;
    }

    // ---- phase 7: ebl hidden (K=512 over concat) ----
    {
      const float4* wT = USET ? wsf4 + OFF_EBL1 / 4 + st * 256 : nullptr;
      const float4* wO = USET ? nullptr
                              : (const float4*)ebl_w1 + (size_t)(st * 256) * 128;
      float acc = run_matvec<256>(s_wbuf, wT, wO, 128, 1024, 128,
                                  (const float4*)s_cat, tid, 0.0f);
      if (tid < kH) s_eblh[tid] = fmaxf(acc, 0.0f);
    }

    // ---- phase 8: ebl out ----
    {
      const float4* wT = USET ? wsf4 + OFF_EBL2 / 4 + st * 256 : nullptr;
      const float4* wO = USET ? nullptr
                              : (const float4*)ebl_w2 + (size_t)(st * 256) * 64;
      float acc = run_matvec<256>(s_wbuf, wT, wO, 64, 1024, 64,
                                  (const float4*)s_eblh, tid, 0.0f);
      if (tid < kH) s_eblo[tid] = acc;
    }

    // ---- LSTM layers: A-chain(wih) + B-chain(whh), 1024 rows/thread ----
    for (int l = 0; l < 2; ++l) {
      const int rowbase = (st * 2 + l) * 1024;
      const float* xe = (l == 0) ? s_eblo : s_h0;
      const float* xh = a0f ? s_ones : ((l == 0) ? s_h0 : s_h1);
      float accA, accB;
      {
        const float4* wT = USET ? wsf4 + OFF_WIH / 4 + rowbase : nullptr;
        const float4* wO = USET ? nullptr
                                : (const float4*)lstm_wih + (size_t)rowbase * 64;
        accA = run_matvec<1024>(s_wbuf, wT, wO, 64, 8192, 64,
                                (const float4*)xe, tid, 0.0f);
      }
      {
        const float4* wT = USET ? wsf4 + OFF_WHH / 4 + rowbase : nullptr;
        const float4* wO = USET ? nullptr
                                : (const float4*)lstm_whh + (size_t)rowbase * 64;
        accB = run_matvec<1024>(s_wbuf, wT, wO, 64, 8192, 64,
                                (const float4*)xh, tid, 0.0f);
      }
      s_gate[tid] = __fadd_rn(accA, accB);
      __syncthreads();
      if (tid < kH) {
        float gi = s_gate[tid], gf = s_gate[256 + tid];
        float gg = s_gate[512 + tid], go = s_gate[768 + tid];
        float* sc = (l == 0) ? s_c0 : s_c1;
        float* sh = (l == 0) ? s_h0 : s_h1;
        float cprev = a0f ? 1.0f : sc[tid];
        float cl = __fadd_rn(__fmul_rn(sig_np(gf), cprev),
                             __fmul_rn(sig_np(gi), tanhf(gg)));
        float hl = __fmul_rn(sig_np(go), tanhf(cl));
        sc[tid] = cl; sh[tid] = hl;
      }
      __syncthreads();
    }

    // ---- stage head weights (used later) + LayerNorm ----
    if (tid < 1536)
      s_hw[tid] = (tid < 768) ? dm_w2[st * 768 + tid]
                              : dv_w2[st * 768 + tid - 768];
    if (tid == 0) s_mu = __fdiv_rn(np_sum256(s_h1), 256.0f);
    __syncthreads();
    if (tid < kH) {
      float d = __fadd_rn(s_h1[tid], -s_mu);
      s_tmp[tid] = d;
      s_tmp[256 + tid] = __fmul_rn(d, d);
    }
    __syncthreads();
    if (tid == 0) {
      float v = __fdiv_rn(np_sum256(s_tmp + 256), 256.0f);
      s_den = __fsqrt_rn(__fadd_rn(v, 1e-5f));
    }
    __syncthreads();
    if (tid < kH) {
      float r = __fadd_rn(__fdiv_rn(s_tmp[tid], s_den), s_eblo[tid]);
      s_r[tid] = fmaxf(r, 0.0f);
    }
    __syncthreads();

    // ---- dm / dv hidden (staged) ----
    {
      const float4* wT = USET ? wsf4 + OFF_DM1 / 4 + st * 256 : nullptr;
      const float4* wO = USET ? nullptr
                              : (const float4*)dm_w1 + (size_t)(st * 256) * 64;
      float acc = run_matvec<256>(s_wbuf, wT, wO, 64, 1024, 64,
                                  (const float4*)s_r, tid, 0.0f);
      if (tid < kH) s_dmh[tid] = fmaxf(acc, 0.0f);
    }
    {
      const float4* wT = USET ? wsf4 + OFF_DV1 / 4 + st * 256 : nullptr;
      const float4* wO = USET ? nullptr
                              : (const float4*)dv_w1 + (size_t)(st * 256) * 64;
      float acc = run_matvec<256>(s_wbuf, wT, wO, 64, 1024, 64,
                                  (const float4*)s_r, tid, 0.0f);
      if (tid < kH) s_dvh[tid] = fmaxf(acc, 0.0f);
    }
    __syncthreads();

    // ---- heads: 6 rows, exact ascending chains from LDS ----
    if (tid < 6) {
      const int d = tid % 3; const bool isv = tid >= 3;
      const float4* w4 = (const float4*)(s_hw + (isv ? 768 : 0) + d * 256);
      const float4* xx = (const float4*)(isv ? s_dvh : s_dmh);
      float acc = 0.0f;
      for (int i = 0; i < 64; ++i) fma4(acc, w4[i], xx[i]);
      s_g6[tid] = acc;
    }
    __syncthreads();

    // ---- anchor update + outputs ----
    if (tid == 0) {
      const float dlmf[3] = {2.0f, 2.0f, 0.5f};
      for (int d = 0; d < 3; ++d) {
        float avn = __fadd_rn(s_anchor[d], __fmul_rn(tanhf(s_g6[d]), dlmf[d]));
        float vvn = __fmul_rn(sig_np(s_g6[3 + d]), 0.1f);
        s_anchor[d] = avn;
        int o = ((b * 4 + st) * 8 + (a + 1)) * 3 + d;
        g_out[o] = avn;
        g_out[6144 + o] = vvn;
        if (a == 6 && st < 3) {
          int o2 = ((b * 4 + st + 1) * 8 + 0) * 3 + d;
          g_out[o2] = avn;
          g_out[6144 + o2] = vvn;
        }
      }
      s_cs[0] = (float)cos((double)s_anchor[2]);
      s_cs[1] = (float)sin((double)s_anchor[2]);
    }
    __syncthreads();
  }
}

extern "C" void kernel_launch(void* const* d_in, const int* in_sizes, int n_in,
                              void* d_out, int out_size, void* d_ws, size_t ws_size,
                              hipStream_t stream) {
  (void)in_sizes; (void)n_in; (void)out_size;
  const int useT = (d_ws != nullptr && ws_size >= WS_FLOATS * sizeof(float)) ? 1 : 0;
  float* wsf = (float*)d_ws;

  if (useT) {
    TransArgs ta;
    const float* srcs[9] = {
        (const float*)d_in[3],  (const float*)d_in[5],  (const float*)d_in[6],
        (const float*)d_in[7],  (const float*)d_in[8],  (const float*)d_in[11],
        (const float*)d_in[13], (const float*)d_in[9],  (const float*)d_in[10]};
    float* dsts[9] = {
        wsf + OFF_ELA2, wsf + OFF_ELM1, wsf + OFF_ELM2, wsf + OFF_EBL1,
        wsf + OFF_EBL2, wsf + OFF_DM1,  wsf + OFF_DV1,  wsf + OFF_WIH,
        wsf + OFF_WHH};
    const int n4s[9] = {65536, 1048576, 65536, 131072, 65536, 65536, 65536,
                        524288, 524288};
    const int rms[9] = {1023, 1023, 1023, 1023, 1023, 1023, 1023, 8191, 8191};
    const int rss[9] = {10, 10, 10, 10, 10, 10, 10, 13, 13};
    const int Ks[9]  = {256, 4096, 256, 512, 256, 256, 256, 256, 256};
    for (int m = 0; m < 9; ++m) {
      ta.src[m] = srcs[m]; ta.dst[m] = dsts[m]; ta.n4[m] = n4s[m];
      ta.rmask[m] = rms[m]; ta.rshift[m] = rss[m]; ta.K[m] = Ks[m];
    }
    transpose_all<<<dim3(1024), dim3(256), 0, stream>>>(ta);

    planner_kernel<1><<<dim3(NWG), dim3(WGSZ), 0, stream>>>(
        (const float*)d_in[0],  (const float*)d_in[1],  (const float*)d_in[2],
        (const float*)d_in[3],  (const float*)d_in[4],  (const float*)d_in[5],
        (const float*)d_in[6],  (const float*)d_in[7],  (const float*)d_in[8],
        (const float*)d_in[9],  (const float*)d_in[10], (const float*)d_in[11],
        (const float*)d_in[12], (const float*)d_in[13], (const float*)d_in[14],
        (const float*)wsf, (float*)d_out);
  } else {
    planner_kernel<0><<<dim3(NWG), dim3(WGSZ), 0, stream>>>(
        (const float*)d_in[0],  (const float*)d_in[1],  (const float*)d_in[2],
        (const float*)d_in[3],  (const float*)d_in[4],  (const float*)d_in[5],
        (const float*)d_in[6],  (const float*)d_in[7],  (const float*)d_in[8],
        (const float*)d_in[9],  (const float*)d_in[10], (const float*)d_in[11],
        (const float*)d_in[12], (const float*)d_in[13], (const float*)d_in[14],
        (const float*)wsf, (float*)d_out);
  }
}